// Round 1
// baseline (1076.329 us; speedup 1.0000x reference)
//
#include <hip/hip_runtime.h>
#include <math.h>

// ---------------------------------------------------------------------------
// EEG StandAlone Attention stem: 3x (attention_stem -> bn_relu -> pool),
// final AvgPool2d((1,56)).
//
// Key simplification: v_agg windows are 1x1 convs of the padded input with
// per-tap effective weights  vw_eff[t] = sum_m softmax_m(emb)[m,t] * vw[m].
// So per stage:
//   q = x . qw                       [B,Co,Ho,Wo]
//   k = xp . kw                      [B,Co,Hp,Wp]   (padded grid, zeros OOB)
//   scores[b,h,w,t] = sum_o q * k[h+dk,w+dl] ; attn = softmax_t
//   out[b,o,h,w] = sum_t attn[t] * sum_c xp[b,c,h+dk,w+dl] * vw_eff[t,c,o]
// ---------------------------------------------------------------------------

#define TPB 256

// ---- per-stage prep: mixture softmax + effective value weights -------------
__global__ void prep_vweff_kernel(const float* __restrict__ ea,   // [Co,kh]
                                  const float* __restrict__ eb,   // [Co,kw]
                                  const float* __restrict__ em,   // [M,Co]
                                  const float* __restrict__ vw,   // [M,Cin,Co]
                                  float* __restrict__ vweff,      // [K,Cin,Co]
                                  int Co, int kh, int kw, int Cin) {
    const int M = 4;
    __shared__ float la[8];    // [m*kh+k]
    __shared__ float lb[20];   // [m*kw+l]
    __shared__ float embs[40]; // [t*4+m]
    int K = kh * kw;
    int tid = threadIdx.x;
    if (tid < M * kh) {
        int m = tid / kh, k = tid % kh;
        float s = 0.f;
        for (int o = 0; o < Co; ++o) s += em[m * Co + o] * ea[o * kh + k];
        la[tid] = s;
    }
    if (tid >= 64 && tid < 64 + M * kw) {
        int r = tid - 64;
        int m = r / kw, l = r % kw;
        float s = 0.f;
        for (int o = 0; o < Co; ++o) s += em[m * Co + o] * eb[o * kw + l];
        lb[r] = s;
    }
    __syncthreads();
    if (tid < K) {
        int k = tid / kw, l = tid % kw;
        float lg[4];
        float mx = -1e30f;
        for (int m = 0; m < M; ++m) {
            lg[m] = la[m * kh + k] + lb[m * kw + l];
            mx = fmaxf(mx, lg[m]);
        }
        float sum = 0.f;
        for (int m = 0; m < M; ++m) { lg[m] = expf(lg[m] - mx); sum += lg[m]; }
        float inv = 1.f / sum;
        for (int m = 0; m < M; ++m) embs[tid * 4 + m] = lg[m] * inv;
    }
    __syncthreads();
    int CC = Cin * Co;
    int total = K * CC;
    for (int e = tid; e < total; e += blockDim.x) {
        int t = e / CC;
        int rem = e - t * CC;
        float s = 0.f;
        for (int m = 0; m < M; ++m) s += embs[t * 4 + m] * vw[m * CC + rem];
        vweff[e] = s;
    }
}

// ---- q and k 1x1 convs in one launch ---------------------------------------
__global__ void qk_kernel(const float* __restrict__ x,   // [B,Cin,H,W]
                          const float* __restrict__ qw,  // [Cin,Co]
                          const float* __restrict__ kw_, // [Cin,Co]
                          float* __restrict__ q,         // [B,Co,Ho,Wo]
                          float* __restrict__ k,         // [B,Co,Hp,Wp]
                          int B, int Cin, int H, int W,
                          int Co, int Ho, int Wo, int Hp, int Wp,
                          int pt, int pl) {
    int idx = blockIdx.x * blockDim.x + threadIdx.x;
    int Nq = B * Co * Ho * Wo;
    int Nk = B * Co * Hp * Wp;
    int HW = H * W;
    if (idx < Nq) {
        int w = idx % Wo; int r = idx / Wo;
        int h = r % Ho; r /= Ho;
        int o = r % Co; int b = r / Co;
        const float* xb = x + (long long)b * Cin * HW + h * W + w;
        float s = 0.f;
        for (int c = 0; c < Cin; ++c) s = fmaf(xb[c * HW], qw[c * Co + o], s);
        q[idx] = s;
    } else if (idx < Nq + Nk) {
        int j = idx - Nq;
        int w = j % Wp; int r = j / Wp;
        int h = r % Hp; r /= Hp;
        int o = r % Co; int b = r / Co;
        int row = h - pt, col = w - pl;
        float s = 0.f;
        if (row >= 0 && row < H && col >= 0 && col < W) {
            const float* xb = x + (long long)b * Cin * HW + row * W + col;
            for (int c = 0; c < Cin; ++c) s = fmaf(xb[c * HW], kw_[c * Co + o], s);
        }
        k[j] = s;
    }
}

// ---- scores + softmax ------------------------------------------------------
template <int KH, int KW>
__global__ void attn_kernel(const float* __restrict__ q,    // [B,Co,Ho,Wo]
                            const float* __restrict__ k,    // [B,Co,Hp,Wp]
                            float* __restrict__ attn,       // [B,K,Ho,Wo]
                            int B, int Co, int Ho, int Wo, int Hp, int Wp) {
    const int K = KH * KW;
    int idx = blockIdx.x * blockDim.x + threadIdx.x;
    int N = B * Ho * Wo;
    if (idx >= N) return;
    int w = idx % Wo; int r = idx / Wo;
    int h = r % Ho; int b = r / Ho;
    float s[K];
#pragma unroll
    for (int t = 0; t < K; ++t) s[t] = 0.f;
    for (int o = 0; o < Co; ++o) {
        float qv = q[((b * Co + o) * Ho + h) * Wo + w];
        const float* kb = k + ((long long)(b * Co + o) * Hp) * Wp + w;
#pragma unroll
        for (int dk = 0; dk < KH; ++dk) {
            const float* krow = kb + (h + dk) * Wp;
#pragma unroll
            for (int dl = 0; dl < KW; ++dl)
                s[dk * KW + dl] = fmaf(qv, krow[dl], s[dk * KW + dl]);
        }
    }
    float mx = s[0];
#pragma unroll
    for (int t = 1; t < K; ++t) mx = fmaxf(mx, s[t]);
    float sum = 0.f;
#pragma unroll
    for (int t = 0; t < K; ++t) { s[t] = expf(s[t] - mx); sum += s[t]; }
    float inv = 1.f / sum;
#pragma unroll
    for (int t = 0; t < K; ++t)
        attn[((b * K + t) * Ho + h) * Wo + w] = s[t] * inv;
}

// ---- attention-weighted value output ---------------------------------------
template <int KH, int KW>
__global__ void out_kernel(const float* __restrict__ x,      // [B,Cin,H,W] (stage input)
                           const float* __restrict__ vweff,  // [K,Cin,Co]
                           const float* __restrict__ attn,   // [B,K,Ho,Wo]
                           float* __restrict__ out,          // [B,Co,Ho,Wo]
                           int B, int Cin, int H, int W,
                           int Co, int Ho, int Wo,
                           int pt, int pl) {
    const int K = KH * KW;
    int idx = blockIdx.x * blockDim.x + threadIdx.x;
    int N = B * Co * Ho * Wo;
    if (idx >= N) return;
    int w = idx % Wo; int r = idx / Wo;
    int h = r % Ho; r /= Ho;
    int o = r % Co; int b = r / Co;
    int HW = H * W;
    const float* xbase = x + (long long)b * Cin * HW;
    float acc = 0.f;
#pragma unroll
    for (int dk = 0; dk < KH; ++dk) {
        int row = h + dk - pt;
        if (row < 0 || row >= H) continue;
#pragma unroll
        for (int dl = 0; dl < KW; ++dl) {
            int col = w + dl - pl;
            if (col < 0 || col >= W) continue;
            int t = dk * KW + dl;
            float a = attn[((b * K + t) * Ho + h) * Wo + w];
            const float* xb = xbase + row * W + col;
            const float* ve = vweff + (long long)t * Cin * Co + o;
            float p = 0.f;
            for (int c = 0; c < Cin; ++c) p = fmaf(xb[c * HW], ve[c * Co], p);
            acc = fmaf(a, p, acc);
        }
    }
    out[idx] = acc;
}

// ---- batchnorm statistics (training mode, biased var) ----------------------
__global__ void bn_stats_kernel(const float* __restrict__ x, // [B,C,HW]
                                float* __restrict__ mr,      // [2*C]: mean, rstd
                                int B, int C, int HW) {
    int c = blockIdx.x;
    int tid = threadIdx.x;
    int N = B * HW;
    double s = 0.0, s2 = 0.0;
    for (int i = tid; i < N; i += blockDim.x) {
        int b = i / HW, r = i - b * HW;
        float v = x[((long long)b * C + c) * HW + r];
        s += v; s2 += (double)v * v;
    }
    __shared__ double sh[TPB], sh2[TPB];
    sh[tid] = s; sh2[tid] = s2;
    __syncthreads();
    for (int st = TPB / 2; st > 0; st >>= 1) {
        if (tid < st) { sh[tid] += sh[tid + st]; sh2[tid] += sh2[tid + st]; }
        __syncthreads();
    }
    if (tid == 0) {
        double mean = sh[0] / N;
        double var = sh2[0] / N - mean * mean;
        mr[c] = (float)mean;
        mr[C + c] = (float)(1.0 / sqrt(var + 1e-5));
    }
}

// ---- bn + relu + stride-2 subsample ----------------------------------------
__global__ void bn_pool_kernel(const float* __restrict__ x,  // [B,C,H,W]
                               const float* __restrict__ mr,
                               const float* __restrict__ g,
                               const float* __restrict__ bb,
                               float* __restrict__ y,        // [B,C,H2,W2]
                               int B, int C, int H, int W, int H2, int W2) {
    int idx = blockIdx.x * blockDim.x + threadIdx.x;
    int N = B * C * H2 * W2;
    if (idx >= N) return;
    int w2 = idx % W2; int r = idx / W2;
    int h2 = r % H2; r /= H2;
    int c = r % C; int b = r / C;
    float v = x[(((long long)b * C + c) * H + 2 * h2) * W + 2 * w2];
    float yn = (v - mr[c]) * mr[C + c] * g[c] + bb[c];
    y[idx] = fmaxf(yn, 0.f);
}

// ---- final bn + relu + AvgPool(1,56) ---------------------------------------
__global__ void bn_avg_final_kernel(const float* __restrict__ x, // [B,C,1,W]
                                    const float* __restrict__ mr,
                                    const float* __restrict__ g,
                                    const float* __restrict__ bb,
                                    float* __restrict__ out,     // [B,C,1,nW]
                                    int B, int C, int W, int nW) {
    int idx = blockIdx.x * blockDim.x + threadIdx.x;
    int N = B * C * nW;
    if (idx >= N) return;
    int j = idx % nW; int r = idx / nW;
    int c = r % C; int b = r / C;
    float mean = mr[c], rstd = mr[C + c], gg = g[c], bo = bb[c];
    const float* xb = x + ((long long)b * C + c) * W + j * 56;
    float s = 0.f;
    for (int i = 0; i < 56; ++i) {
        float yn = (xb[i] - mean) * rstd * gg + bo;
        s += fmaxf(yn, 0.f);
    }
    out[idx] = s * (1.f / 56.f);
}

// ---------------------------------------------------------------------------
extern "C" void kernel_launch(void* const* d_in, const int* in_sizes, int n_in,
                              void* d_out, int out_size, void* d_ws, size_t ws_size,
                              hipStream_t stream) {
    const float* x   = (const float*)d_in[0];
    // stage 0 params: d_in[1..8], stage1: 9..16, stage2: 17..24
    const float* qw0 = (const float*)d_in[1];
    const float* kw0 = (const float*)d_in[2];
    const float* vw0 = (const float*)d_in[3];
    const float* ea0 = (const float*)d_in[4];
    const float* eb0 = (const float*)d_in[5];
    const float* em0 = (const float*)d_in[6];
    const float* g0  = (const float*)d_in[7];
    const float* b0  = (const float*)d_in[8];
    const float* qw1 = (const float*)d_in[9];
    const float* kw1 = (const float*)d_in[10];
    const float* vw1 = (const float*)d_in[11];
    const float* ea1 = (const float*)d_in[12];
    const float* eb1 = (const float*)d_in[13];
    const float* em1 = (const float*)d_in[14];
    const float* g1  = (const float*)d_in[15];
    const float* b1  = (const float*)d_in[16];
    const float* qw2 = (const float*)d_in[17];
    const float* kw2 = (const float*)d_in[18];
    const float* vw2 = (const float*)d_in[19];
    const float* ea2 = (const float*)d_in[20];
    const float* eb2 = (const float*)d_in[21];
    const float* em2 = (const float*)d_in[22];
    const float* g2  = (const float*)d_in[23];
    const float* b2  = (const float*)d_in[24];
    float* outp = (float*)d_out;

    float* ws = (float*)d_ws;
    size_t off = 0;
    auto alloc = [&](size_t n) { float* p = ws + off; off += (n + 63) & ~(size_t)63; return p; };

    // ---- buffers ----
    float* vweff0 = alloc(5 * 1 * 64);
    float* q0     = alloc(2 * 64 * 8 * 3000);
    float* k0     = alloc(2 * 64 * 8 * 3004);
    float* attn0  = alloc(2 * 5 * 8 * 3000);
    float* s0     = alloc(2 * 64 * 8 * 3000);
    float* mr0    = alloc(2 * 64);
    float* h0     = alloc(2 * 64 * 4 * 1500);

    float* vweff1 = alloc(10 * 64 * 128);
    float* q1     = alloc(2 * 128 * 4 * 1500);
    float* k1     = alloc(2 * 128 * 6 * 1504);
    float* attn1  = alloc(2 * 10 * 4 * 1500);
    float* s1     = alloc(2 * 128 * 4 * 1500);
    float* mr1    = alloc(2 * 128);
    float* h1     = alloc(2 * 128 * 2 * 750);

    float* vweff2 = alloc(10 * 128 * 16);
    float* q2     = alloc(2 * 16 * 1 * 750);
    float* k2     = alloc(2 * 16 * 2 * 754);
    float* attn2  = alloc(2 * 10 * 1 * 750);
    float* s2     = alloc(2 * 16 * 1 * 750);
    float* mr2    = alloc(2 * 16);
    (void)ws_size; (void)in_sizes; (void)n_in; (void)out_size;

    auto grid = [](int n) { return (n + TPB - 1) / TPB; };

    // ======== stage 0: B=2 Cin=1 H=8 W=3000, Co=64, kh=1 kw=5, pad(l2,r2,t0,b0)
    // Hp=8 Wp=3004 Ho=8 Wo=3000
    prep_vweff_kernel<<<1, TPB, 0, stream>>>(ea0, eb0, em0, vw0, vweff0, 64, 1, 5, 1);
    {
        int Nq = 2 * 64 * 8 * 3000, Nk = 2 * 64 * 8 * 3004;
        qk_kernel<<<grid(Nq + Nk), TPB, 0, stream>>>(x, qw0, kw0, q0, k0,
            2, 1, 8, 3000, 64, 8, 3000, 8, 3004, 0, 2);
    }
    attn_kernel<1, 5><<<grid(2 * 8 * 3000), TPB, 0, stream>>>(q0, k0, attn0,
        2, 64, 8, 3000, 8, 3004);
    out_kernel<1, 5><<<grid(2 * 64 * 8 * 3000), TPB, 0, stream>>>(x, vweff0, attn0, s0,
        2, 1, 8, 3000, 64, 8, 3000, 0, 2);
    bn_stats_kernel<<<64, TPB, 0, stream>>>(s0, mr0, 2, 64, 8 * 3000);
    bn_pool_kernel<<<grid(2 * 64 * 4 * 1500), TPB, 0, stream>>>(s0, mr0, g0, b0, h0,
        2, 64, 8, 3000, 4, 1500);

    // ======== stage 1: B=2 Cin=64 H=4 W=1500, Co=128, kh=2 kw=5, pad(l2,r2,t1,b1)
    // Hp=6 Wp=1504 Ho=4 Wo=1500
    prep_vweff_kernel<<<1, TPB, 0, stream>>>(ea1, eb1, em1, vw1, vweff1, 128, 2, 5, 64);
    {
        int Nq = 2 * 128 * 4 * 1500, Nk = 2 * 128 * 6 * 1504;
        qk_kernel<<<grid(Nq + Nk), TPB, 0, stream>>>(h0, qw1, kw1, q1, k1,
            2, 64, 4, 1500, 128, 4, 1500, 6, 1504, 1, 2);
    }
    attn_kernel<2, 5><<<grid(2 * 4 * 1500), TPB, 0, stream>>>(q1, k1, attn1,
        2, 128, 4, 1500, 6, 1504);
    out_kernel<2, 5><<<grid(2 * 128 * 4 * 1500), TPB, 0, stream>>>(h0, vweff1, attn1, s1,
        2, 64, 4, 1500, 128, 4, 1500, 1, 2);
    bn_stats_kernel<<<128, TPB, 0, stream>>>(s1, mr1, 2, 128, 4 * 1500);
    bn_pool_kernel<<<grid(2 * 128 * 2 * 750), TPB, 0, stream>>>(s1, mr1, g1, b1, h1,
        2, 128, 4, 1500, 2, 750);

    // ======== stage 2: B=2 Cin=128 H=2 W=750, Co=16, kh=2 kw=5, pad(l2,r2,t0,b0)
    // Hp=2 Wp=754 Ho=1 Wo=750
    prep_vweff_kernel<<<1, TPB, 0, stream>>>(ea2, eb2, em2, vw2, vweff2, 16, 2, 5, 128);
    {
        int Nq = 2 * 16 * 1 * 750, Nk = 2 * 16 * 2 * 754;
        qk_kernel<<<grid(Nq + Nk), TPB, 0, stream>>>(h1, qw2, kw2, q2, k2,
            2, 128, 2, 750, 16, 1, 750, 2, 754, 0, 2);
    }
    attn_kernel<2, 5><<<grid(2 * 1 * 750), TPB, 0, stream>>>(q2, k2, attn2,
        2, 16, 1, 750, 2, 754);
    out_kernel<2, 5><<<grid(2 * 16 * 1 * 750), TPB, 0, stream>>>(h1, vweff2, attn2, s2,
        2, 128, 2, 750, 16, 1, 750, 0, 2);
    bn_stats_kernel<<<16, TPB, 0, stream>>>(s2, mr2, 2, 16, 750);
    bn_avg_final_kernel<<<grid(2 * 16 * 13), TPB, 0, stream>>>(s2, mr2, g2, b2, outp,
        2, 16, 750, 13);
}

// Round 2
// 416.927 us; speedup vs baseline: 2.5816x; 2.5816x over previous
//
#include <hip/hip_runtime.h>
#include <math.h>

// ---------------------------------------------------------------------------
// EEG StandAlone Attention stem, GEMM-structured.
//
// Per stage: stack [qw; kw; vweff(t)] into Wcat[M][Cin] and do ONE tiled GEMM
//   C = Wcat . X   (X = stage input, channel-major [b][c][hw])
// Epilogue: rows < 2*Co -> qk buffer, spatial-major [b][n][2Co] (fast attn);
//           rows >= 2*Co -> z buffer, channel-major [b][t*Co+o][n].
// attn: per (b,h,w) contiguous float4 dot products + softmax over K taps.
// combine: out[b,o,h,w] = sum_t attn[t] * z[t*Co+o, shifted n]  (coalesced).
// vweff[t] = sum_m softmax_m(emb)[m,t] * vw[m]  (mixture folded into weights).
// ---------------------------------------------------------------------------

#define TPB 256

// ---- stage0 helper: mixture softmax + effective value weights --------------
__global__ void prep_vweff_kernel(const float* __restrict__ ea,   // [Co,kh]
                                  const float* __restrict__ eb,   // [Co,kw]
                                  const float* __restrict__ em,   // [M,Co]
                                  const float* __restrict__ vw,   // [M,Cin,Co]
                                  float* __restrict__ vweff,      // [K,Cin,Co]
                                  int Co, int kh, int kw, int Cin) {
    const int M4 = 4;
    __shared__ float la[8];
    __shared__ float lb[20];
    __shared__ float embs[40];
    int K = kh * kw;
    int tid = threadIdx.x;
    if (tid < M4 * kh) {
        int m = tid / kh, k = tid % kh;
        float s = 0.f;
        for (int o = 0; o < Co; ++o) s += em[m * Co + o] * ea[o * kh + k];
        la[tid] = s;
    }
    if (tid >= 64 && tid < 64 + M4 * kw) {
        int r = tid - 64;
        int m = r / kw, l = r % kw;
        float s = 0.f;
        for (int o = 0; o < Co; ++o) s += em[m * Co + o] * eb[o * kw + l];
        lb[r] = s;
    }
    __syncthreads();
    if (tid < K) {
        int k = tid / kw, l = tid % kw;
        float lg[4];
        float mx = -1e30f;
        for (int m = 0; m < M4; ++m) {
            lg[m] = la[m * kh + k] + lb[m * kw + l];
            mx = fmaxf(mx, lg[m]);
        }
        float sum = 0.f;
        for (int m = 0; m < M4; ++m) { lg[m] = expf(lg[m] - mx); sum += lg[m]; }
        float inv = 1.f / sum;
        for (int m = 0; m < M4; ++m) embs[tid * 4 + m] = lg[m] * inv;
    }
    __syncthreads();
    int CC = Cin * Co;
    int total = K * CC;
    for (int e = tid; e < total; e += blockDim.x) {
        int t = e / CC;
        int rem = e - t * CC;
        float s = 0.f;
        for (int m = 0; m < M4; ++m) s += embs[t * 4 + m] * vw[m * CC + rem];
        vweff[e] = s;
    }
}

// ---- stages 1/2: build stacked weight matrix Wcat[(2+K)*Co][Cin] -----------
__global__ void prep_wcat_kernel(const float* __restrict__ ea,
                                 const float* __restrict__ eb,
                                 const float* __restrict__ em,
                                 const float* __restrict__ qw,   // [Cin,Co]
                                 const float* __restrict__ kw_,  // [Cin,Co]
                                 const float* __restrict__ vw,   // [M,Cin,Co]
                                 float* __restrict__ Wcat,       // [(2+K)*Co][Cin]
                                 int Co, int kh, int kw, int Cin) {
    const int M4 = 4;
    __shared__ float la[8];
    __shared__ float lb[20];
    __shared__ float embs[40];
    int K = kh * kw;
    int tid = threadIdx.x;
    if (tid < M4 * kh) {
        int m = tid / kh, k = tid % kh;
        float s = 0.f;
        for (int o = 0; o < Co; ++o) s += em[m * Co + o] * ea[o * kh + k];
        la[tid] = s;
    }
    if (tid >= 64 && tid < 64 + M4 * kw) {
        int r = tid - 64;
        int m = r / kw, l = r % kw;
        float s = 0.f;
        for (int o = 0; o < Co; ++o) s += em[m * Co + o] * eb[o * kw + l];
        lb[r] = s;
    }
    __syncthreads();
    if (tid < K) {
        int k = tid / kw, l = tid % kw;
        float lg[4];
        float mx = -1e30f;
        for (int m = 0; m < M4; ++m) {
            lg[m] = la[m * kh + k] + lb[m * kw + l];
            mx = fmaxf(mx, lg[m]);
        }
        float sum = 0.f;
        for (int m = 0; m < M4; ++m) { lg[m] = expf(lg[m] - mx); sum += lg[m]; }
        float inv = 1.f / sum;
        for (int m = 0; m < M4; ++m) embs[tid * 4 + m] = lg[m] * inv;
    }
    __syncthreads();
    int Mtot = (2 + K) * Co;
    long long total = (long long)Mtot * Cin;
    for (long long e = (long long)blockIdx.x * blockDim.x + tid; e < total;
         e += (long long)gridDim.x * blockDim.x) {
        int m = (int)(e / Cin);
        int c = (int)(e - (long long)m * Cin);
        float val;
        if (m < Co) {
            val = qw[c * Co + m];
        } else if (m < 2 * Co) {
            val = kw_[c * Co + (m - Co)];
        } else {
            int mz = m - 2 * Co;
            int t = mz / Co;
            int o = mz - t * Co;
            val = 0.f;
            for (int mm = 0; mm < M4; ++mm)
                val += embs[t * 4 + mm] * vw[(mm * Cin + c) * Co + o];
        }
        Wcat[e] = val;
    }
}

// ---- stage0 q/k (Cin=1), spatial-major output ------------------------------
__global__ void qk0_kernel(const float* __restrict__ x,    // [2*24000] flat
                           const float* __restrict__ qw,   // [64]
                           const float* __restrict__ kw_,  // [64]
                           float* __restrict__ qk) {       // [n][128]
    __shared__ float wv[128];
    __shared__ float xs[64];
    int tid = threadIdx.x;
    if (tid < 128) wv[tid] = (tid < 64) ? qw[tid] : kw_[tid - 64];
    int n0 = blockIdx.x * 64;
    if (tid < 64) xs[tid] = x[n0 + tid];
    __syncthreads();
#pragma unroll
    for (int it = 0; it < 8; ++it) {
        int f = it * 256 + tid;
        int nl = f >> 5;
        int m4 = (f & 31) * 4;
        float xv = xs[nl];
        float4 w4 = *(const float4*)&wv[m4];
        *(float4*)&qk[((size_t)(n0 + nl)) * 128 + m4] =
            make_float4(xv * w4.x, xv * w4.y, xv * w4.z, xv * w4.w);
    }
}

// ---- tiled GEMM: C = Wcat(MxK) . X(KxN), split epilogue --------------------
__launch_bounds__(256)
__global__ void gemm_qkz_kernel(const float* __restrict__ A,  // [M][K]
                                const float* __restrict__ X,  // [b][K][N]
                                float* __restrict__ qk,       // [b][N][2Co]
                                float* __restrict__ z,        // [b][M-2Co][N]
                                int M, int N, int K, int twoCo) {
    __shared__ float As[64][68];
    __shared__ float Bs[64][68];
    int tid = threadIdx.x;
    int b = blockIdx.z;
    int m0 = blockIdx.y * 64, n0 = blockIdx.x * 64;
    int Mz = M - twoCo;
    float acc[4][4] = {{0.f}};
    int am = tid >> 2;            // 0..63
    int aq = (tid & 3) * 16;      // quarter offset
    int tm4 = (tid & 15) * 4;     // micro m
    int tn4 = (tid >> 4) * 4;     // micro n

    for (int k0 = 0; k0 < K; k0 += 64) {
        // stage A: As[k][m] = A[m0+m][k0+k]  (transpose in)
        const float* Ap = A + (size_t)(m0 + am) * K + k0 + aq;
#pragma unroll
        for (int qd = 0; qd < 4; ++qd) {
            float4 v = *(const float4*)(Ap + qd * 4);
            int kk = aq + qd * 4;
            As[kk + 0][am] = v.x;
            As[kk + 1][am] = v.y;
            As[kk + 2][am] = v.z;
            As[kk + 3][am] = v.w;
        }
        // stage B: Bs[k][n] = X[b][k0+k][n0+n]
        const float* Xp = X + (size_t)b * K * N + (size_t)(k0 + am) * N + n0 + aq;
        if (n0 + 64 <= N) {
#pragma unroll
            for (int qd = 0; qd < 4; ++qd) {
                float4 v = *(const float4*)(Xp + qd * 4);
                *(float4*)&Bs[am][aq + qd * 4] = v;
            }
        } else {
#pragma unroll
            for (int j = 0; j < 16; ++j) {
                int n = n0 + aq + j;
                Bs[am][aq + j] = (n < N) ? Xp[j] : 0.f;
            }
        }
        __syncthreads();
#pragma unroll 16
        for (int k = 0; k < 64; ++k) {
            float4 a4 = *(const float4*)&As[k][tm4];
            float4 b4 = *(const float4*)&Bs[k][tn4];
            float av[4] = {a4.x, a4.y, a4.z, a4.w};
            float bv[4] = {b4.x, b4.y, b4.z, b4.w};
#pragma unroll
            for (int i = 0; i < 4; ++i)
#pragma unroll
                for (int j = 0; j < 4; ++j)
                    acc[i][j] = fmaf(av[i], bv[j], acc[i][j]);
        }
        __syncthreads();
    }
    // epilogue
#pragma unroll
    for (int i = 0; i < 4; ++i) {
        int m = m0 + tm4 + i;
        if (m < twoCo) {
#pragma unroll
            for (int j = 0; j < 4; ++j) {
                int n = n0 + tn4 + j;
                if (n < N) qk[((size_t)b * N + n) * twoCo + m] = acc[i][j];
            }
        } else {
            int n = n0 + tn4;
            if (n < N)
                *(float4*)&z[((size_t)(b * Mz + (m - twoCo))) * N + n] =
                    make_float4(acc[i][0], acc[i][1], acc[i][2], acc[i][3]);
        }
    }
}

// ---- attention scores + softmax, spatial-major q/k -------------------------
template <int KH, int KW, int CO>
__global__ void attn_v2_kernel(const float* __restrict__ qk,  // [b][HWin][2CO]
                               float* __restrict__ attn,      // [b][K][HoWo]
                               int B, int H, int W, int Ho, int Wo,
                               int pt, int pl) {
    const int K = KH * KW;
    int idx = blockIdx.x * blockDim.x + threadIdx.x;
    int Nout = Ho * Wo;
    if (idx >= B * Nout) return;
    int wo = idx % Wo;
    int r = idx / Wo;
    int ho = r % Ho;
    int b = r / Ho;
    int HWin = H * W;
    const float* qp = qk + (size_t)((long long)b * HWin + ho * W + wo) * (2 * CO);
    const float* kp[K];
    bool val[K];
#pragma unroll
    for (int dk = 0; dk < KH; ++dk)
#pragma unroll
        for (int dl = 0; dl < KW; ++dl) {
            int t = dk * KW + dl;
            int row = ho + dk - pt, col = wo + dl - pl;
            val[t] = (row >= 0 && row < H && col >= 0 && col < W);
            long long off = ((long long)b * HWin + (long long)row * W + col) * (2 * CO) + CO;
            kp[t] = qk + off;
        }
    float s[K];
#pragma unroll
    for (int t = 0; t < K; ++t) s[t] = 0.f;
    for (int o = 0; o < CO; o += 4) {
        float4 q4 = *(const float4*)(qp + o);
#pragma unroll
        for (int t = 0; t < K; ++t) {
            if (val[t]) {
                float4 k4 = *(const float4*)(kp[t] + o);
                s[t] += q4.x * k4.x + q4.y * k4.y + q4.z * k4.z + q4.w * k4.w;
            }
        }
    }
    float mx = s[0];
#pragma unroll
    for (int t = 1; t < K; ++t) mx = fmaxf(mx, s[t]);
    float sum = 0.f;
#pragma unroll
    for (int t = 0; t < K; ++t) { s[t] = expf(s[t] - mx); sum += s[t]; }
    float inv = 1.f / sum;
    int nout = ho * Wo + wo;
#pragma unroll
    for (int t = 0; t < K; ++t)
        attn[((size_t)b * K + t) * Nout + nout] = s[t] * inv;
}

// ---- stage0 attention-weighted output (Cin=1) ------------------------------
template <int KH, int KW>
__global__ void out_kernel(const float* __restrict__ x,      // [B,1,H,W]
                           const float* __restrict__ vweff,  // [K,1,Co]
                           const float* __restrict__ attn,   // [B,K,HoWo]
                           float* __restrict__ out,          // [B,Co,HoWo]
                           int B, int Cin, int H, int W,
                           int Co, int Ho, int Wo,
                           int pt, int pl) {
    const int K = KH * KW;
    int idx = blockIdx.x * blockDim.x + threadIdx.x;
    int N = B * Co * Ho * Wo;
    if (idx >= N) return;
    int w = idx % Wo; int r = idx / Wo;
    int h = r % Ho; r /= Ho;
    int o = r % Co; int b = r / Co;
    int HW = H * W;
    const float* xbase = x + (long long)b * Cin * HW;
    float acc = 0.f;
#pragma unroll
    for (int dk = 0; dk < KH; ++dk) {
        int row = h + dk - pt;
        if (row < 0 || row >= H) continue;
#pragma unroll
        for (int dl = 0; dl < KW; ++dl) {
            int col = w + dl - pl;
            if (col < 0 || col >= W) continue;
            int t = dk * KW + dl;
            float a = attn[((b * K + t) * Ho + h) * Wo + w];
            float p = 0.f;
            for (int c = 0; c < Cin; ++c)
                p = fmaf(xbase[c * HW + row * W + col], vweff[((long long)t * Cin + c) * Co + o], p);
            acc = fmaf(a, p, acc);
        }
    }
    out[idx] = acc;
}

// ---- combine: out = sum_t attn[t] * shifted z[t] ---------------------------
template <int KH, int KW>
__global__ void combine_kernel(const float* __restrict__ z,     // [b][Mz][HWin]
                               const float* __restrict__ attn,  // [b][K][HoWo]
                               float* __restrict__ out,         // [b][Co][HoWo]
                               int B, int Co, int Mz,
                               int H, int W, int Ho, int Wo,
                               int pt, int pl) {
    const int K = KH * KW;
    int idx = blockIdx.x * blockDim.x + threadIdx.x;
    int N = B * Co * Ho * Wo;
    if (idx >= N) return;
    int wo = idx % Wo; int r = idx / Wo;
    int ho = r % Ho; r /= Ho;
    int o = r % Co; int b = r / Co;
    int Nin = H * W, Nout = Ho * Wo;
    int nout = ho * Wo + wo;
    float acc = 0.f;
#pragma unroll
    for (int dk = 0; dk < KH; ++dk) {
        int row = ho + dk - pt;
        if (row < 0 || row >= H) continue;
#pragma unroll
        for (int dl = 0; dl < KW; ++dl) {
            int col = wo + dl - pl;
            if (col < 0 || col >= W) continue;
            int t = dk * KW + dl;
            float a = attn[((size_t)b * K + t) * Nout + nout];
            float zv = z[((size_t)b * Mz + t * Co + o) * Nin + row * W + col];
            acc = fmaf(a, zv, acc);
        }
    }
    out[idx] = acc;
}

// ---- batchnorm statistics --------------------------------------------------
__global__ void bn_stats_kernel(const float* __restrict__ x, // [B,C,HW]
                                float* __restrict__ mr,      // [2*C]
                                int B, int C, int HW) {
    int c = blockIdx.x;
    int tid = threadIdx.x;
    int N = B * HW;
    double s = 0.0, s2 = 0.0;
    for (int i = tid; i < N; i += blockDim.x) {
        int b = i / HW, r = i - b * HW;
        float v = x[((long long)b * C + c) * HW + r];
        s += v; s2 += (double)v * v;
    }
    __shared__ double sh[TPB], sh2[TPB];
    sh[tid] = s; sh2[tid] = s2;
    __syncthreads();
    for (int st = TPB / 2; st > 0; st >>= 1) {
        if (tid < st) { sh[tid] += sh[tid + st]; sh2[tid] += sh2[tid + st]; }
        __syncthreads();
    }
    if (tid == 0) {
        double mean = sh[0] / N;
        double var = sh2[0] / N - mean * mean;
        mr[c] = (float)mean;
        mr[C + c] = (float)(1.0 / sqrt(var + 1e-5));
    }
}

// ---- bn + relu + stride-2 subsample ----------------------------------------
__global__ void bn_pool_kernel(const float* __restrict__ x,  // [B,C,H,W]
                               const float* __restrict__ mr,
                               const float* __restrict__ g,
                               const float* __restrict__ bb,
                               float* __restrict__ y,        // [B,C,H2,W2]
                               int B, int C, int H, int W, int H2, int W2) {
    int idx = blockIdx.x * blockDim.x + threadIdx.x;
    int N = B * C * H2 * W2;
    if (idx >= N) return;
    int w2 = idx % W2; int r = idx / W2;
    int h2 = r % H2; r /= H2;
    int c = r % C; int b = r / C;
    float v = x[(((long long)b * C + c) * H + 2 * h2) * W + 2 * w2];
    float yn = (v - mr[c]) * mr[C + c] * g[c] + bb[c];
    y[idx] = fmaxf(yn, 0.f);
}

// ---- final bn + relu + AvgPool(1,56) ---------------------------------------
__global__ void bn_avg_final_kernel(const float* __restrict__ x, // [B,C,1,W]
                                    const float* __restrict__ mr,
                                    const float* __restrict__ g,
                                    const float* __restrict__ bb,
                                    float* __restrict__ out,     // [B,C,1,nW]
                                    int B, int C, int W, int nW) {
    int idx = blockIdx.x * blockDim.x + threadIdx.x;
    int N = B * C * nW;
    if (idx >= N) return;
    int j = idx % nW; int r = idx / nW;
    int c = r % C; int b = r / C;
    float mean = mr[c], rstd = mr[C + c], gg = g[c], bo = bb[c];
    const float* xb = x + ((long long)b * C + c) * W + j * 56;
    float s = 0.f;
    for (int i = 0; i < 56; ++i) {
        float yn = (xb[i] - mean) * rstd * gg + bo;
        s += fmaxf(yn, 0.f);
    }
    out[idx] = s * (1.f / 56.f);
}

// ---------------------------------------------------------------------------
extern "C" void kernel_launch(void* const* d_in, const int* in_sizes, int n_in,
                              void* d_out, int out_size, void* d_ws, size_t ws_size,
                              hipStream_t stream) {
    const float* x   = (const float*)d_in[0];
    const float* qw0 = (const float*)d_in[1];
    const float* kw0 = (const float*)d_in[2];
    const float* vw0 = (const float*)d_in[3];
    const float* ea0 = (const float*)d_in[4];
    const float* eb0 = (const float*)d_in[5];
    const float* em0 = (const float*)d_in[6];
    const float* g0  = (const float*)d_in[7];
    const float* b0  = (const float*)d_in[8];
    const float* qw1 = (const float*)d_in[9];
    const float* kw1 = (const float*)d_in[10];
    const float* vw1 = (const float*)d_in[11];
    const float* ea1 = (const float*)d_in[12];
    const float* eb1 = (const float*)d_in[13];
    const float* em1 = (const float*)d_in[14];
    const float* g1  = (const float*)d_in[15];
    const float* b1  = (const float*)d_in[16];
    const float* qw2 = (const float*)d_in[17];
    const float* kw2 = (const float*)d_in[18];
    const float* vw2 = (const float*)d_in[19];
    const float* ea2 = (const float*)d_in[20];
    const float* eb2 = (const float*)d_in[21];
    const float* em2 = (const float*)d_in[22];
    const float* g2  = (const float*)d_in[23];
    const float* b2  = (const float*)d_in[24];
    float* outp = (float*)d_out;
    (void)ws_size; (void)in_sizes; (void)n_in; (void)out_size;

    float* ws = (float*)d_ws;
    size_t off = 0;
    auto alloc = [&](size_t n) { float* p = ws + off; off += (n + 63) & ~(size_t)63; return p; };

    // Arena: z1 (15.36M floats) overlaps qk0 (6.144M, dead after attn0) and
    // s0 (3.072M, dead after bn_pool0 -- before the stage-1 GEMM writes z1).
    float* arena = alloc(2 * 1280 * 6000);          // 15,360,000
    float* qk0   = arena;                           // [48000][128]
    float* s0    = arena + 2 * 64 * 24000 * 0 + 6144000; // [2][64][24000]
    float* z1    = arena;                           // [2][1280][6000]

    float* vweff0 = alloc(5 * 64);
    float* attn0  = alloc(2 * 5 * 24000);
    float* mr0    = alloc(2 * 64);
    float* h0     = alloc(2 * 64 * 6000);           // [2][64][4*1500]
    float* Wcat1  = alloc(1536 * 64);
    float* qk1    = alloc(2 * 6000 * 256);          // [2][6000][256]
    float* attn1  = alloc(2 * 10 * 6000);
    float* s1     = alloc(2 * 128 * 6000);
    float* mr1    = alloc(2 * 128);
    float* h1     = alloc(2 * 128 * 1500);          // [2][128][2*750]
    float* Wcat2  = alloc(192 * 128);
    float* qk2    = alloc(2 * 1500 * 32);           // [2][1500][32]
    float* z2     = alloc(2 * 160 * 1500);
    float* attn2  = alloc(2 * 10 * 750);
    float* s2     = alloc(2 * 16 * 750);
    float* mr2    = alloc(2 * 16);

    auto grid = [](int n) { return (n + TPB - 1) / TPB; };

    // ======== stage 0: B=2 Cin=1 H=8 W=3000, Co=64, kh=1 kw=5, pad(2,2,0,0)
    prep_vweff_kernel<<<1, TPB, 0, stream>>>(ea0, eb0, em0, vw0, vweff0, 64, 1, 5, 1);
    qk0_kernel<<<750, TPB, 0, stream>>>(x, qw0, kw0, qk0);
    attn_v2_kernel<1, 5, 64><<<grid(2 * 24000), TPB, 0, stream>>>(qk0, attn0,
        2, 8, 3000, 8, 3000, 0, 2);
    out_kernel<1, 5><<<grid(2 * 64 * 24000), TPB, 0, stream>>>(x, vweff0, attn0, s0,
        2, 1, 8, 3000, 64, 8, 3000, 0, 2);
    bn_stats_kernel<<<64, TPB, 0, stream>>>(s0, mr0, 2, 64, 24000);
    bn_pool_kernel<<<grid(2 * 64 * 6000), TPB, 0, stream>>>(s0, mr0, g0, b0, h0,
        2, 64, 8, 3000, 4, 1500);

    // ======== stage 1: Cin=64 H=4 W=1500, Co=128, kh=2 kw=5, pad(2,2,1,1)
    prep_wcat_kernel<<<96, TPB, 0, stream>>>(ea1, eb1, em1, qw1, kw1, vw1, Wcat1,
        128, 2, 5, 64);
    {
        dim3 g((6000 + 63) / 64, 1536 / 64, 2);
        gemm_qkz_kernel<<<g, TPB, 0, stream>>>(Wcat1, h0, qk1, z1, 1536, 6000, 64, 256);
    }
    attn_v2_kernel<2, 5, 128><<<grid(2 * 6000), TPB, 0, stream>>>(qk1, attn1,
        2, 4, 1500, 4, 1500, 1, 2);
    combine_kernel<2, 5><<<grid(2 * 128 * 6000), TPB, 0, stream>>>(z1, attn1, s1,
        2, 128, 1280, 4, 1500, 4, 1500, 1, 2);
    bn_stats_kernel<<<128, TPB, 0, stream>>>(s1, mr1, 2, 128, 6000);
    bn_pool_kernel<<<grid(2 * 128 * 1500), TPB, 0, stream>>>(s1, mr1, g1, b1, h1,
        2, 128, 4, 1500, 2, 750);

    // ======== stage 2: Cin=128 H=2 W=750, Co=16, kh=2 kw=5, pad(2,2,0,0)
    prep_wcat_kernel<<<24, TPB, 0, stream>>>(ea2, eb2, em2, qw2, kw2, vw2, Wcat2,
        16, 2, 5, 128);
    {
        dim3 g((1500 + 63) / 64, 192 / 64, 2);
        gemm_qkz_kernel<<<g, TPB, 0, stream>>>(Wcat2, h1, qk2, z2, 192, 1500, 128, 32);
    }
    attn_v2_kernel<2, 5, 16><<<grid(2 * 750), TPB, 0, stream>>>(qk2, attn2,
        2, 2, 750, 1, 750, 0, 2);
    combine_kernel<2, 5><<<grid(2 * 16 * 750), TPB, 0, stream>>>(z2, attn2, s2,
        2, 16, 160, 2, 750, 1, 750, 0, 2);
    bn_stats_kernel<<<16, TPB, 0, stream>>>(s2, mr2, 2, 16, 750);
    bn_avg_final_kernel<<<grid(2 * 16 * 13), TPB, 0, stream>>>(s2, mr2, g2, b2, outp,
        2, 16, 750, 13);
}

// Round 3
// 287.761 us; speedup vs baseline: 3.7404x; 1.4489x over previous
//
#include <hip/hip_runtime.h>
#include <math.h>

// ---------------------------------------------------------------------------
// EEG StandAlone Attention stem.
// Stage 0 (Cin=1) collapses: score[t] = c0 * x[n] * x_shift[t], c0=dot(qw,kw).
// Stages 1/2: Wcat=[qw;kw;vweff(t)] -> one 128x128-tile GEMM -> qk(spatial) +
// z(channel) -> parallel attn -> combine. BN stats via 2-phase reduction.
// ---------------------------------------------------------------------------

#define TPB 256

// ---- stage0 prep: c0 = dot(qw,kw), vweff[5][64] ----------------------------
__global__ void prep0_kernel(const float* __restrict__ ea,   // [64,1]
                             const float* __restrict__ eb,   // [64,5]
                             const float* __restrict__ em,   // [4,64]
                             const float* __restrict__ qw,   // [1,64]
                             const float* __restrict__ kw_,  // [1,64]
                             const float* __restrict__ vw,   // [4,1,64]
                             float* __restrict__ par) {      // [0]=c0, [1+t*64+o]
    const int M4 = 4, Co = 64, kh = 1, kw = 5;
    __shared__ float la[4];
    __shared__ float lb[20];
    __shared__ float embs[20]; // [t*4+m], K=5
    int tid = threadIdx.x;
    if (tid < 64) {
        float p = qw[tid] * kw_[tid];
#pragma unroll
        for (int d = 1; d < 64; d <<= 1) p += __shfl_xor(p, d, 64);
        if (tid == 0) par[0] = p;
    }
    if (tid >= 64 && tid < 64 + M4) {  // la[m] (kh=1)
        int m = tid - 64;
        float s = 0.f;
        for (int o = 0; o < Co; ++o) s += em[m * Co + o] * ea[o];
        la[m] = s;
    }
    if (tid >= 128 && tid < 128 + M4 * kw) {
        int r = tid - 128;
        int m = r / kw, l = r % kw;
        float s = 0.f;
        for (int o = 0; o < Co; ++o) s += em[m * Co + o] * eb[o * kw + l];
        lb[m * kw + l] = s;
    }
    __syncthreads();
    if (tid < 5) {
        float lg[4];
        float mx = -1e30f;
        for (int m = 0; m < M4; ++m) {
            lg[m] = la[m] + lb[m * kw + tid];
            mx = fmaxf(mx, lg[m]);
        }
        float sum = 0.f;
        for (int m = 0; m < M4; ++m) { lg[m] = expf(lg[m] - mx); sum += lg[m]; }
        float inv = 1.f / sum;
        for (int m = 0; m < M4; ++m) embs[tid * 4 + m] = lg[m] * inv;
    }
    __syncthreads();
    for (int e = tid; e < 5 * 64; e += blockDim.x) {
        int t = e / 64, o = e - t * 64;
        float s = 0.f;
        for (int m = 0; m < M4; ++m) s += embs[t * 4 + m] * vw[m * 64 + o];
        par[1 + e] = s;
    }
}

// ---- stages 1/2: build stacked weight matrix Wcat[(2+K)*Co][Cin] -----------
__global__ void prep_wcat_kernel(const float* __restrict__ ea,
                                 const float* __restrict__ eb,
                                 const float* __restrict__ em,
                                 const float* __restrict__ qw,   // [Cin,Co]
                                 const float* __restrict__ kw_,  // [Cin,Co]
                                 const float* __restrict__ vw,   // [M,Cin,Co]
                                 float* __restrict__ Wcat,       // [(2+K)*Co][Cin]
                                 int Co, int kh, int kw, int Cin) {
    const int M4 = 4;
    __shared__ float la[8];
    __shared__ float lb[20];
    __shared__ float embs[40];
    int K = kh * kw;
    int tid = threadIdx.x;
    if (tid < M4 * kh) {
        int m = tid / kh, k = tid % kh;
        float s = 0.f;
        for (int o = 0; o < Co; ++o) s += em[m * Co + o] * ea[o * kh + k];
        la[tid] = s;
    }
    if (tid >= 64 && tid < 64 + M4 * kw) {
        int r = tid - 64;
        int m = r / kw, l = r % kw;
        float s = 0.f;
        for (int o = 0; o < Co; ++o) s += em[m * Co + o] * eb[o * kw + l];
        lb[r] = s;
    }
    __syncthreads();
    if (tid < K) {
        int k = tid / kw, l = tid % kw;
        float lg[4];
        float mx = -1e30f;
        for (int m = 0; m < M4; ++m) {
            lg[m] = la[m * kh + k] + lb[m * kw + l];
            mx = fmaxf(mx, lg[m]);
        }
        float sum = 0.f;
        for (int m = 0; m < M4; ++m) { lg[m] = expf(lg[m] - mx); sum += lg[m]; }
        float inv = 1.f / sum;
        for (int m = 0; m < M4; ++m) embs[tid * 4 + m] = lg[m] * inv;
    }
    __syncthreads();
    int Mtot = (2 + K) * Co;
    long long total = (long long)Mtot * Cin;
    for (long long e = (long long)blockIdx.x * blockDim.x + tid; e < total;
         e += (long long)gridDim.x * blockDim.x) {
        int m = (int)(e / Cin);
        int c = (int)(e - (long long)m * Cin);
        float val;
        if (m < Co) {
            val = qw[c * Co + m];
        } else if (m < 2 * Co) {
            val = kw_[c * Co + (m - Co)];
        } else {
            int mz = m - 2 * Co;
            int t = mz / Co;
            int o = mz - t * Co;
            val = 0.f;
            for (int mm = 0; mm < M4; ++mm)
                val += embs[t * 4 + mm] * vw[(mm * Cin + c) * Co + o];
        }
        Wcat[e] = val;
    }
}

// ---- stage0 fused attention + output (Cin=1) -------------------------------
// score[t] = c0 * x[n] * xs[t]; attn = softmax_t; out[o,n] = sum_t attn*xs*vweff[t,o]
__global__ void attn_out0_kernel(const float* __restrict__ x,   // [2][8][3000]
                                 const float* __restrict__ par, // c0 + vweff
                                 float* __restrict__ s0) {      // [2][64][24000]
    __shared__ float wsh[5][256];
    __shared__ float vsh[5 * 64];
    int tid = threadIdx.x;
    int b = blockIdx.y;
    int n0 = blockIdx.x * 256;
    int n = n0 + tid;
    for (int i = tid; i < 320; i += 256) vsh[i] = par[1 + i];
    float c0 = par[0];
    if (n < 24000) {
        int h = n / 3000, w = n - h * 3000;
        const float* xr = x + b * 24000 + h * 3000;
        float xc = xr[w];
        float xs[5], s[5];
#pragma unroll
        for (int t = 0; t < 5; ++t) {
            int col = w + t - 2;
            xs[t] = (col >= 0 && col < 3000) ? xr[col] : 0.f;
            s[t] = c0 * xc * xs[t];
        }
        float mx = s[0];
#pragma unroll
        for (int t = 1; t < 5; ++t) mx = fmaxf(mx, s[t]);
        float sum = 0.f;
#pragma unroll
        for (int t = 0; t < 5; ++t) { s[t] = expf(s[t] - mx); sum += s[t]; }
        float inv = 1.f / sum;
#pragma unroll
        for (int t = 0; t < 5; ++t) wsh[t][tid] = s[t] * inv * xs[t];
    } else {
#pragma unroll
        for (int t = 0; t < 5; ++t) wsh[t][tid] = 0.f;
    }
    __syncthreads();
    // phase 2: thread -> (n-quad jq, o-group og of 16)
    int jq = tid & 63, og = tid >> 6;
    int nq = n0 + jq * 4;
    if (nq < 24000) {
        float wq[5][4];
#pragma unroll
        for (int t = 0; t < 5; ++t)
#pragma unroll
            for (int j = 0; j < 4; ++j) wq[t][j] = wsh[t][jq * 4 + j];
        int obase = og * 16;
        for (int oi = 0; oi < 16; ++oi) {
            int o = obase + oi;
            float4 v;
            v.x = 0.f; v.y = 0.f; v.z = 0.f; v.w = 0.f;
#pragma unroll
            for (int t = 0; t < 5; ++t) {
                float vo = vsh[t * 64 + o];
                v.x = fmaf(wq[t][0], vo, v.x);
                v.y = fmaf(wq[t][1], vo, v.y);
                v.z = fmaf(wq[t][2], vo, v.z);
                v.w = fmaf(wq[t][3], vo, v.w);
            }
            *(float4*)&s0[((size_t)b * 64 + o) * 24000 + nq] = v;
        }
    }
}

// ---- tiled GEMM v2: 128x128 tile, 8x8 microtile, BK=64 ---------------------
__launch_bounds__(256, 2)
__global__ void gemm_qkz_kernel(const float* __restrict__ A,  // [M][K]
                                const float* __restrict__ X,  // [b][K][N]
                                float* __restrict__ qk,       // [b][N][2Co]
                                float* __restrict__ z,        // [b][M-2Co][N]
                                int M, int N, int K, int twoCo) {
    __shared__ float As[64][132];
    __shared__ float Bs[64][132];
    int tid = threadIdx.x;
    int b = blockIdx.z;
    int m0 = blockIdx.y * 128, n0 = blockIdx.x * 128;
    int Mz = M - twoCo;
    float acc[8][8] = {{0.f}};
    int am = tid >> 1, ak = (tid & 1) * 32;
    int bk = tid >> 2, bn = (tid & 3) * 32;
    int tm = tid & 15, tn = tid >> 4;   // microtile coords

    for (int k0 = 0; k0 < K; k0 += 64) {
        // A-tile: As[k][m] = A[m0+m][k0+k] (transposed)
        {
            int mA = m0 + am;
            const float* Ap = A + (size_t)mA * K + k0 + ak;
#pragma unroll
            for (int q = 0; q < 8; ++q) {
                float4 v = (mA < M) ? *(const float4*)(Ap + q * 4)
                                    : make_float4(0.f, 0.f, 0.f, 0.f);
                int kk = ak + q * 4;
                As[kk + 0][am] = v.x;
                As[kk + 1][am] = v.y;
                As[kk + 2][am] = v.z;
                As[kk + 3][am] = v.w;
            }
        }
        // B-tile: Bs[k][n] = X[b][k0+k][n0+n]
        {
            const float* Xp = X + (size_t)b * K * N + (size_t)(k0 + bk) * N + n0 + bn;
            if (n0 + 128 <= N) {
#pragma unroll
                for (int q = 0; q < 8; ++q)
                    *(float4*)&Bs[bk][bn + q * 4] = *(const float4*)(Xp + q * 4);
            } else {
#pragma unroll
                for (int q = 0; q < 8; ++q)
#pragma unroll
                    for (int j = 0; j < 4; ++j) {
                        int n = n0 + bn + q * 4 + j;
                        Bs[bk][bn + q * 4 + j] = (n < N) ? Xp[q * 4 + j] : 0.f;
                    }
            }
        }
        __syncthreads();
#pragma unroll 16
        for (int k = 0; k < 64; ++k) {
            float4 a0 = *(const float4*)&As[k][tm * 8];
            float4 a1 = *(const float4*)&As[k][tm * 8 + 4];
            float4 b0 = *(const float4*)&Bs[k][tn * 8];
            float4 b1 = *(const float4*)&Bs[k][tn * 8 + 4];
            float av[8] = {a0.x, a0.y, a0.z, a0.w, a1.x, a1.y, a1.z, a1.w};
            float bv[8] = {b0.x, b0.y, b0.z, b0.w, b1.x, b1.y, b1.z, b1.w};
#pragma unroll
            for (int i = 0; i < 8; ++i)
#pragma unroll
                for (int j = 0; j < 8; ++j)
                    acc[i][j] = fmaf(av[i], bv[j], acc[i][j]);
        }
        __syncthreads();
    }
    // epilogue
    bool fullN = (n0 + 128 <= N);
#pragma unroll
    for (int i = 0; i < 8; ++i) {
        int m = m0 + tm * 8 + i;
        if (m >= M) continue;
        if (m < twoCo) {
#pragma unroll
            for (int j = 0; j < 8; ++j) {
                int n = n0 + tn * 8 + j;
                if (n < N) qk[((size_t)b * N + n) * twoCo + m] = acc[i][j];
            }
        } else {
            float* zp = &z[((size_t)b * Mz + (m - twoCo)) * N + n0 + tn * 8];
            if (fullN) {
                *(float4*)zp = make_float4(acc[i][0], acc[i][1], acc[i][2], acc[i][3]);
                *(float4*)(zp + 4) = make_float4(acc[i][4], acc[i][5], acc[i][6], acc[i][7]);
            } else {
#pragma unroll
                for (int j = 0; j < 8; ++j) {
                    int n = n0 + tn * 8 + j;
                    if (n < N) zp[j] = acc[i][j];
                }
            }
        }
    }
}

// ---- attention scores + softmax, thread per (n, tap) -----------------------
template <int KH, int KW, int CO, int NPB>
__global__ void attn_v3_kernel(const float* __restrict__ qk,  // [b][HWin][2CO]
                               float* __restrict__ attn,      // [b][K][Nout]
                               int H, int W, int Ho, int Wo, int pt, int pl) {
    const int K = KH * KW;
    __shared__ float ssh[NPB][K];
    int tid = threadIdx.x;
    int b = blockIdx.y;
    int ln = tid / K, t = tid - ln * K;
    int Nout = Ho * Wo;
    int n = blockIdx.x * NPB + ln;
    bool active = (tid < NPB * K) && (n < Nout);
    int HWin = H * W;
    float sv = 0.f;
    int ho = 0, wo = 0;
    if (active) {
        ho = n / Wo; wo = n - ho * Wo;
        int row = ho + t / KW - pt, col = wo + t % KW - pl;
        if (row >= 0 && row < H && col >= 0 && col < W) {
            const float* qp = qk + ((size_t)b * HWin + ho * W + wo) * (2 * CO);
            const float* kp = qk + ((size_t)b * HWin + (size_t)row * W + col) * (2 * CO) + CO;
#pragma unroll
            for (int o = 0; o < CO; o += 4) {
                float4 q4 = *(const float4*)(qp + o);
                float4 k4 = *(const float4*)(kp + o);
                sv += q4.x * k4.x + q4.y * k4.y + q4.z * k4.z + q4.w * k4.w;
            }
        }
        ssh[ln][t] = sv;
    }
    __syncthreads();
    if (active) {
        float mx = ssh[ln][0];
#pragma unroll
        for (int tt = 1; tt < K; ++tt) mx = fmaxf(mx, ssh[ln][tt]);
        float sum = 0.f;
#pragma unroll
        for (int tt = 0; tt < K; ++tt) sum += expf(ssh[ln][tt] - mx);
        float num = expf(sv - mx);
        attn[((size_t)b * K + t) * Nout + n] = num / sum;
    }
}

// ---- combine: out = sum_t attn[t] * shifted z[t] ---------------------------
template <int KH, int KW>
__global__ void combine_kernel(const float* __restrict__ z,     // [b][Mz][HWin]
                               const float* __restrict__ attn,  // [b][K][Nout]
                               float* __restrict__ out,         // [b][Co][Nout]
                               int B, int Co, int Mz,
                               int H, int W, int Ho, int Wo,
                               int pt, int pl) {
    const int K = KH * KW;
    int idx = blockIdx.x * blockDim.x + threadIdx.x;
    int N = B * Co * Ho * Wo;
    if (idx >= N) return;
    int wo = idx % Wo; int r = idx / Wo;
    int ho = r % Ho; r /= Ho;
    int o = r % Co; int b = r / Co;
    int Nin = H * W, Nout = Ho * Wo;
    int nout = ho * Wo + wo;
    float acc = 0.f;
#pragma unroll
    for (int dk = 0; dk < KH; ++dk) {
        int row = ho + dk - pt;
        if (row < 0 || row >= H) continue;
#pragma unroll
        for (int dl = 0; dl < KW; ++dl) {
            int col = wo + dl - pl;
            if (col < 0 || col >= W) continue;
            int t = dk * KW + dl;
            float a = attn[((size_t)b * K + t) * Nout + nout];
            float zv = z[((size_t)b * Mz + t * Co + o) * Nin + row * W + col];
            acc = fmaf(a, zv, acc);
        }
    }
    out[idx] = acc;
}

// ---- BN stats, phase A: per-(channel,chunk) partial sums -------------------
__global__ void bn_partial_kernel(const float* __restrict__ x,  // [B][C][HW]
                                  float2* __restrict__ part,    // [C][NCH]
                                  int B, int C, int HW, int len) {
    int c = blockIdx.x, ch = blockIdx.y, NCH = gridDim.y;
    int tid = threadIdx.x;
    int start = ch * len;
    int end = min(HW, start + len);
    float s = 0.f, s2 = 0.f;
    bool vec = ((HW & 3) == 0) && ((len & 3) == 0);
    for (int b = 0; b < B; ++b) {
        const float* xp = x + ((size_t)b * C + c) * HW;
        if (vec) {
            for (int i = start + tid * 4; i < end; i += TPB * 4) {
                float4 v = *(const float4*)(xp + i);
                s += v.x + v.y + v.z + v.w;
                s2 += v.x * v.x + v.y * v.y + v.z * v.z + v.w * v.w;
            }
        } else {
            for (int i = start + tid; i < end; i += TPB) {
                float v = xp[i];
                s += v; s2 += v * v;
            }
        }
    }
    __shared__ float sh[TPB], sh2[TPB];
    sh[tid] = s; sh2[tid] = s2;
    __syncthreads();
    for (int st = TPB / 2; st > 0; st >>= 1) {
        if (tid < st) { sh[tid] += sh[tid + st]; sh2[tid] += sh2[tid + st]; }
        __syncthreads();
    }
    if (tid == 0) part[c * NCH + ch] = make_float2(sh[0], sh2[0]);
}

// ---- BN stats, phase B: finalize mean/rstd ---------------------------------
__global__ void bn_final_kernel(const float2* __restrict__ part,
                                float* __restrict__ mr,  // [2C]
                                int C, int NCH, int B, int HW) {
    int c = threadIdx.x;
    if (c >= C) return;
    double s = 0.0, s2 = 0.0;
    for (int i = 0; i < NCH; ++i) {
        float2 p = part[c * NCH + i];
        s += p.x; s2 += p.y;
    }
    double N = (double)B * HW;
    double mean = s / N;
    double var = s2 / N - mean * mean;
    mr[c] = (float)mean;
    mr[C + c] = (float)(1.0 / sqrt(var + 1e-5));
}

// ---- bn + relu + stride-2 subsample ----------------------------------------
__global__ void bn_pool_kernel(const float* __restrict__ x,  // [B,C,H,W]
                               const float* __restrict__ mr,
                               const float* __restrict__ g,
                               const float* __restrict__ bb,
                               float* __restrict__ y,        // [B,C,H2,W2]
                               int B, int C, int H, int W, int H2, int W2) {
    int idx = blockIdx.x * blockDim.x + threadIdx.x;
    int N = B * C * H2 * W2;
    if (idx >= N) return;
    int w2 = idx % W2; int r = idx / W2;
    int h2 = r % H2; r /= H2;
    int c = r % C; int b = r / C;
    float v = x[(((long long)b * C + c) * H + 2 * h2) * W + 2 * w2];
    float yn = (v - mr[c]) * mr[C + c] * g[c] + bb[c];
    y[idx] = fmaxf(yn, 0.f);
}

// ---- final bn + relu + AvgPool(1,56) ---------------------------------------
__global__ void bn_avg_final_kernel(const float* __restrict__ x, // [B,C,1,W]
                                    const float* __restrict__ mr,
                                    const float* __restrict__ g,
                                    const float* __restrict__ bb,
                                    float* __restrict__ out,     // [B,C,1,nW]
                                    int B, int C, int W, int nW) {
    int idx = blockIdx.x * blockDim.x + threadIdx.x;
    int N = B * C * nW;
    if (idx >= N) return;
    int j = idx % nW; int r = idx / nW;
    int c = r % C; int b = r / C;
    float mean = mr[c], rstd = mr[C + c], gg = g[c], bo = bb[c];
    const float* xb = x + ((long long)b * C + c) * W + j * 56;
    float s = 0.f;
    for (int i = 0; i < 56; ++i) {
        float yn = (xb[i] - mean) * rstd * gg + bo;
        s += fmaxf(yn, 0.f);
    }
    out[idx] = s * (1.f / 56.f);
}

// ---------------------------------------------------------------------------
extern "C" void kernel_launch(void* const* d_in, const int* in_sizes, int n_in,
                              void* d_out, int out_size, void* d_ws, size_t ws_size,
                              hipStream_t stream) {
    const float* x   = (const float*)d_in[0];
    const float* qw0 = (const float*)d_in[1];
    const float* kw0 = (const float*)d_in[2];
    const float* vw0 = (const float*)d_in[3];
    const float* ea0 = (const float*)d_in[4];
    const float* eb0 = (const float*)d_in[5];
    const float* em0 = (const float*)d_in[6];
    const float* g0  = (const float*)d_in[7];
    const float* b0  = (const float*)d_in[8];
    const float* qw1 = (const float*)d_in[9];
    const float* kw1 = (const float*)d_in[10];
    const float* vw1 = (const float*)d_in[11];
    const float* ea1 = (const float*)d_in[12];
    const float* eb1 = (const float*)d_in[13];
    const float* em1 = (const float*)d_in[14];
    const float* g1  = (const float*)d_in[15];
    const float* b1  = (const float*)d_in[16];
    const float* qw2 = (const float*)d_in[17];
    const float* kw2 = (const float*)d_in[18];
    const float* vw2 = (const float*)d_in[19];
    const float* ea2 = (const float*)d_in[20];
    const float* eb2 = (const float*)d_in[21];
    const float* em2 = (const float*)d_in[22];
    const float* g2  = (const float*)d_in[23];
    const float* b2  = (const float*)d_in[24];
    float* outp = (float*)d_out;
    (void)ws_size; (void)in_sizes; (void)n_in; (void)out_size;

    float* ws = (float*)d_ws;
    size_t off = 0;
    auto alloc = [&](size_t n) { float* p = ws + off; off += (n + 63) & ~(size_t)63; return p; };

    // s0 (3.07M, dead before stage-1 GEMM) overlaps z1 (15.36M) in one arena.
    float* arena = alloc(2 * 1280 * 6000);
    float* s0    = arena;                   // [2][64][24000]
    float* z1    = arena;                   // [2][1280][6000]

    float* par0   = alloc(321);             // c0 + vweff0
    float* part   = alloc(2048);            // float2 partials (max 512)
    float* mr0    = alloc(2 * 64);
    float* h0     = alloc(2 * 64 * 6000);   // [2][64][4*1500]
    float* Wcat1  = alloc(1536 * 64);
    float* qk1    = alloc(2 * 6000 * 256);
    float* attn1  = alloc(2 * 10 * 6000);
    float* s1     = alloc(2 * 128 * 6000);
    float* mr1    = alloc(2 * 128);
    float* h1     = alloc(2 * 128 * 1500);
    float* Wcat2  = alloc(192 * 128);
    float* qk2    = alloc(2 * 1500 * 32);
    float* z2     = alloc(2 * 160 * 1500);
    float* attn2  = alloc(2 * 10 * 750);
    float* s2     = alloc(2 * 16 * 750);
    float* mr2    = alloc(2 * 16);

    auto grid = [](int n) { return (n + TPB - 1) / TPB; };

    // ======== stage 0: B=2 Cin=1 H=8 W=3000, Co=64, kh=1 kw=5, pad(2,2,0,0)
    prep0_kernel<<<1, TPB, 0, stream>>>(ea0, eb0, em0, qw0, kw0, vw0, par0);
    {
        dim3 g(94, 2);
        attn_out0_kernel<<<g, TPB, 0, stream>>>(x, par0, s0);
    }
    {
        dim3 g(64, 8);  // C=64, NCH=8, len=3000
        bn_partial_kernel<<<g, TPB, 0, stream>>>(s0, (float2*)part, 2, 64, 24000, 3000);
    }
    bn_final_kernel<<<1, 64, 0, stream>>>((const float2*)part, mr0, 64, 8, 2, 24000);
    bn_pool_kernel<<<grid(2 * 64 * 6000), TPB, 0, stream>>>(s0, mr0, g0, b0, h0,
        2, 64, 8, 3000, 4, 1500);

    // ======== stage 1: Cin=64 H=4 W=1500, Co=128, kh=2 kw=5, pad(2,2,1,1)
    prep_wcat_kernel<<<96, TPB, 0, stream>>>(ea1, eb1, em1, qw1, kw1, vw1, Wcat1,
        128, 2, 5, 64);
    {
        dim3 g((6000 + 127) / 128, 1536 / 128, 2);
        gemm_qkz_kernel<<<g, TPB, 0, stream>>>(Wcat1, h0, qk1, z1, 1536, 6000, 64, 256);
    }
    {
        dim3 g(6000 / 25, 2);
        attn_v3_kernel<2, 5, 128, 25><<<g, TPB, 0, stream>>>(qk1, attn1,
            4, 1500, 4, 1500, 1, 2);
    }
    combine_kernel<2, 5><<<grid(2 * 128 * 6000), TPB, 0, stream>>>(z1, attn1, s1,
        2, 128, 1280, 4, 1500, 4, 1500, 1, 2);
    {
        dim3 g(128, 4);  // C=128, NCH=4, len=1500
        bn_partial_kernel<<<g, TPB, 0, stream>>>(s1, (float2*)part, 2, 128, 6000, 1500);
    }
    bn_final_kernel<<<1, 128, 0, stream>>>((const float2*)part, mr1, 128, 4, 2, 6000);
    bn_pool_kernel<<<grid(2 * 128 * 1500), TPB, 0, stream>>>(s1, mr1, g1, b1, h1,
        2, 128, 4, 1500, 2, 750);

    // ======== stage 2: Cin=128 H=2 W=750, Co=16, kh=2 kw=5, pad(2,2,0,0)
    prep_wcat_kernel<<<24, TPB, 0, stream>>>(ea2, eb2, em2, qw2, kw2, vw2, Wcat2,
        16, 2, 5, 128);
    {
        dim3 g((1500 + 127) / 128, (192 + 127) / 128, 2);
        gemm_qkz_kernel<<<g, TPB, 0, stream>>>(Wcat2, h1, qk2, z2, 192, 1500, 128, 32);
    }
    {
        dim3 g(750 / 25, 2);
        attn_v3_kernel<2, 5, 16, 25><<<g, TPB, 0, stream>>>(qk2, attn2,
            2, 750, 1, 750, 0, 2);
    }
    combine_kernel<2, 5><<<grid(2 * 16 * 750), TPB, 0, stream>>>(z2, attn2, s2,
        2, 16, 160, 2, 750, 1, 750, 0, 2);
    {
        dim3 g(16, 4);  // C=16, NCH=4, len=188 (scalar path, 750%4!=0)
        bn_partial_kernel<<<g, TPB, 0, stream>>>(s2, (float2*)part, 2, 16, 750, 188);
    }
    bn_final_kernel<<<1, 16, 0, stream>>>((const float2*)part, mr2, 16, 4, 2, 750);
    bn_avg_final_kernel<<<grid(2 * 16 * 13), TPB, 0, stream>>>(s2, mr2, g2, b2, outp,
        2, 16, 750, 13);
}

// Round 4
// 282.200 us; speedup vs baseline: 3.8141x; 1.0197x over previous
//
#include <hip/hip_runtime.h>
#include <math.h>

// ---------------------------------------------------------------------------
// EEG StandAlone Attention stem.
// Stage 0 (Cin=1) collapses: score[t] = c0 * x[n] * x_shift[t], c0=dot(qw,kw).
// Stages 1/2: Wcat=[qw;kw;vweff(t)] -> one 128x128 (BK=32) GEMM -> qk(spatial)
// + z(channel) -> attn -> combine(+BN partials). BN finalize folded into the
// next prep kernel / final kernel. 13 launches total.
// ---------------------------------------------------------------------------

#define TPB 256

// ---- stage0 prep: c0 = dot(qw,kw), vweff[5][64] ----------------------------
__global__ void prep0_kernel(const float* __restrict__ ea,   // [64,1]
                             const float* __restrict__ eb,   // [64,5]
                             const float* __restrict__ em,   // [4,64]
                             const float* __restrict__ qw,   // [1,64]
                             const float* __restrict__ kw_,  // [1,64]
                             const float* __restrict__ vw,   // [4,1,64]
                             float* __restrict__ par) {      // [0]=c0, [1+t*64+o]
    const int M4 = 4, Co = 64, kw = 5;
    __shared__ float la[4];
    __shared__ float lb[20];
    __shared__ float embs[20]; // [t*4+m], K=5
    int tid = threadIdx.x;
    if (tid < 64) {
        float p = qw[tid] * kw_[tid];
#pragma unroll
        for (int d = 1; d < 64; d <<= 1) p += __shfl_xor(p, d, 64);
        if (tid == 0) par[0] = p;
    }
    if (tid >= 64 && tid < 64 + M4) {
        int m = tid - 64;
        float s = 0.f;
        for (int o = 0; o < Co; ++o) s += em[m * Co + o] * ea[o];
        la[m] = s;
    }
    if (tid >= 128 && tid < 128 + M4 * kw) {
        int r = tid - 128;
        int m = r / kw, l = r % kw;
        float s = 0.f;
        for (int o = 0; o < Co; ++o) s += em[m * Co + o] * eb[o * kw + l];
        lb[m * kw + l] = s;
    }
    __syncthreads();
    if (tid < 5) {
        float lg[4];
        float mx = -1e30f;
        for (int m = 0; m < M4; ++m) {
            lg[m] = la[m] + lb[m * kw + tid];
            mx = fmaxf(mx, lg[m]);
        }
        float sum = 0.f;
        for (int m = 0; m < M4; ++m) { lg[m] = expf(lg[m] - mx); sum += lg[m]; }
        float inv = 1.f / sum;
        for (int m = 0; m < M4; ++m) embs[tid * 4 + m] = lg[m] * inv;
    }
    __syncthreads();
    for (int e = tid; e < 5 * 64; e += blockDim.x) {
        int t = e / 64, o = e - t * 64;
        float s = 0.f;
        for (int m = 0; m < M4; ++m) s += embs[t * 4 + m] * vw[m * 64 + o];
        par[1 + e] = s;
    }
}

// ---- stages 1/2: Wcat build + (block 0) BN finalize of PREVIOUS stage ------
__global__ void prep_wcat_kernel(const float* __restrict__ ea,
                                 const float* __restrict__ eb,
                                 const float* __restrict__ em,
                                 const float* __restrict__ qw,   // [Cin,Co]
                                 const float* __restrict__ kw_,  // [Cin,Co]
                                 const float* __restrict__ vw,   // [M,Cin,Co]
                                 float* __restrict__ Wcat,       // [(2+K)*Co][Cin]
                                 int Co, int kh, int kw, int Cin,
                                 const float2* __restrict__ part, // prev stage
                                 float* __restrict__ mr,          // [2*Cprev]
                                 int Cprev, int NCH, int count) {
    const int M4 = 4;
    __shared__ float la[8];
    __shared__ float lb[20];
    __shared__ float embs[40];
    int K = kh * kw;
    int tid = threadIdx.x;
    // BN finalize of previous stage (block 0 only)
    if (blockIdx.x == 0 && tid < Cprev) {
        double s = 0.0, s2 = 0.0;
        for (int i = 0; i < NCH; ++i) {
            float2 p = part[(size_t)tid * NCH + i];
            s += p.x; s2 += p.y;
        }
        double mean = s / count;
        double var = s2 / count - mean * mean;
        mr[tid] = (float)mean;
        mr[Cprev + tid] = (float)(1.0 / sqrt(var + 1e-5));
    }
    if (tid < M4 * kh) {
        int m = tid / kh, k = tid % kh;
        float s = 0.f;
        for (int o = 0; o < Co; ++o) s += em[m * Co + o] * ea[o * kh + k];
        la[tid] = s;
    }
    if (tid >= 64 && tid < 64 + M4 * kw) {
        int r = tid - 64;
        int m = r / kw, l = r % kw;
        float s = 0.f;
        for (int o = 0; o < Co; ++o) s += em[m * Co + o] * eb[o * kw + l];
        lb[r] = s;
    }
    __syncthreads();
    if (tid < K) {
        int k = tid / kw, l = tid % kw;
        float lg[4];
        float mx = -1e30f;
        for (int m = 0; m < M4; ++m) {
            lg[m] = la[m * kh + k] + lb[m * kw + l];
            mx = fmaxf(mx, lg[m]);
        }
        float sum = 0.f;
        for (int m = 0; m < M4; ++m) { lg[m] = expf(lg[m] - mx); sum += lg[m]; }
        float inv = 1.f / sum;
        for (int m = 0; m < M4; ++m) embs[tid * 4 + m] = lg[m] * inv;
    }
    __syncthreads();
    int Mtot = (2 + K) * Co;
    long long total = (long long)Mtot * Cin;
    for (long long e = (long long)blockIdx.x * blockDim.x + tid; e < total;
         e += (long long)gridDim.x * blockDim.x) {
        int m = (int)(e / Cin);
        int c = (int)(e - (long long)m * Cin);
        float val;
        if (m < Co) {
            val = qw[c * Co + m];
        } else if (m < 2 * Co) {
            val = kw_[c * Co + (m - Co)];
        } else {
            int mz = m - 2 * Co;
            int t = mz / Co;
            int o = mz - t * Co;
            val = 0.f;
            for (int mm = 0; mm < M4; ++mm)
                val += embs[t * 4 + mm] * vw[(mm * Cin + c) * Co + o];
        }
        Wcat[e] = val;
    }
}

// ---- stage0 fused attention + output + BN partials (Cin=1) -----------------
__global__ void attn_out0_kernel(const float* __restrict__ x,   // [2][8][3000]
                                 const float* __restrict__ par, // c0 + vweff
                                 float* __restrict__ s0,        // [2][64][24000]
                                 float2* __restrict__ part0) {  // [64][188]
    __shared__ float wsh[5][256];
    __shared__ float vsh[5 * 64];
    int tid = threadIdx.x;
    int b = blockIdx.y;
    int n0 = blockIdx.x * 256;
    int n = n0 + tid;
    for (int i = tid; i < 320; i += 256) vsh[i] = par[1 + i];
    float c0 = par[0];
    if (n < 24000) {
        int h = n / 3000, w = n - h * 3000;
        const float* xr = x + b * 24000 + h * 3000;
        float xc = xr[w];
        float xs[5], s[5];
#pragma unroll
        for (int t = 0; t < 5; ++t) {
            int col = w + t - 2;
            xs[t] = (col >= 0 && col < 3000) ? xr[col] : 0.f;
            s[t] = c0 * xc * xs[t];
        }
        float mx = s[0];
#pragma unroll
        for (int t = 1; t < 5; ++t) mx = fmaxf(mx, s[t]);
        float sum = 0.f;
#pragma unroll
        for (int t = 0; t < 5; ++t) { s[t] = expf(s[t] - mx); sum += s[t]; }
        float inv = 1.f / sum;
#pragma unroll
        for (int t = 0; t < 5; ++t) wsh[t][tid] = s[t] * inv * xs[t];
    } else {
#pragma unroll
        for (int t = 0; t < 5; ++t) wsh[t][tid] = 0.f;
    }
    __syncthreads();
    // phase 2: thread -> (n-quad jq, o-group og of 16); wave == og group.
    int jq = tid & 63, og = tid >> 6;
    int nq = n0 + jq * 4;
    bool st = (nq < 24000);
    float wq[5][4];
#pragma unroll
    for (int t = 0; t < 5; ++t)
#pragma unroll
        for (int j = 0; j < 4; ++j) wq[t][j] = wsh[t][jq * 4 + j];
    int obase = og * 16;
    int chunk = b * gridDim.x + blockIdx.x;   // 188 chunks
    for (int oi = 0; oi < 16; ++oi) {
        int o = obase + oi;
        float4 v = make_float4(0.f, 0.f, 0.f, 0.f);
#pragma unroll
        for (int t = 0; t < 5; ++t) {
            float vo = vsh[t * 64 + o];
            v.x = fmaf(wq[t][0], vo, v.x);
            v.y = fmaf(wq[t][1], vo, v.y);
            v.z = fmaf(wq[t][2], vo, v.z);
            v.w = fmaf(wq[t][3], vo, v.w);
        }
        if (st) *(float4*)&s0[((size_t)b * 64 + o) * 24000 + nq] = v;
        float ls = v.x + v.y + v.z + v.w;
        float ls2 = v.x * v.x + v.y * v.y + v.z * v.z + v.w * v.w;
#pragma unroll
        for (int d = 1; d < 64; d <<= 1) {
            ls += __shfl_xor(ls, d, 64);
            ls2 += __shfl_xor(ls2, d, 64);
        }
        if ((tid & 63) == 0)
            part0[(size_t)o * 188 + chunk] = make_float2(ls, ls2);
    }
}

// ---- tiled GEMM v3: 128x128 tile, BK=32, conflict-light microtiles ---------
__launch_bounds__(256, 4)
__global__ void gemm_qkz_kernel(const float* __restrict__ A,  // [M][K]
                                const float* __restrict__ X,  // [b][K][N]
                                float* __restrict__ qk,       // [b][N][2Co]
                                float* __restrict__ z,        // [b][M-2Co][N]
                                int M, int N, int K, int twoCo) {
    __shared__ float As[32][132];
    __shared__ float Bs[32][132];
    int tid = threadIdx.x;
    int b = blockIdx.z;
    int m0 = blockIdx.y * 128, n0 = blockIdx.x * 128;
    int Mz = M - twoCo;
    float acc[8][8] = {{0.f}};
    int am = tid >> 1, ak = (tid & 1) * 16;
    int bk = tid >> 3, bn = (tid & 7) * 16;
    int tm = tid & 15, tn = tid >> 4;

    for (int k0 = 0; k0 < K; k0 += 32) {
        {
            int mA = m0 + am;
            const float* Ap = A + (size_t)mA * K + k0 + ak;
#pragma unroll
            for (int q = 0; q < 4; ++q) {
                float4 v = (mA < M) ? *(const float4*)(Ap + q * 4)
                                    : make_float4(0.f, 0.f, 0.f, 0.f);
                int kk = ak + q * 4;
                As[kk + 0][am] = v.x;
                As[kk + 1][am] = v.y;
                As[kk + 2][am] = v.z;
                As[kk + 3][am] = v.w;
            }
        }
        {
            const float* Xp = X + (size_t)b * K * N + (size_t)(k0 + bk) * N + n0 + bn;
            if (n0 + 128 <= N) {
#pragma unroll
                for (int q = 0; q < 4; ++q)
                    *(float4*)&Bs[bk][bn + q * 4] = *(const float4*)(Xp + q * 4);
            } else {
#pragma unroll
                for (int q = 0; q < 16; ++q) {
                    int n = n0 + bn + q;
                    Bs[bk][bn + q] = (n < N) ? Xp[q] : 0.f;
                }
            }
        }
        __syncthreads();
#pragma unroll 8
        for (int k = 0; k < 32; ++k) {
            float4 a0 = *(const float4*)&As[k][tm * 4];
            float4 a1 = *(const float4*)&As[k][64 + tm * 4];
            float4 b0 = *(const float4*)&Bs[k][tn * 4];
            float4 b1 = *(const float4*)&Bs[k][64 + tn * 4];
            float av[8] = {a0.x, a0.y, a0.z, a0.w, a1.x, a1.y, a1.z, a1.w};
            float bv[8] = {b0.x, b0.y, b0.z, b0.w, b1.x, b1.y, b1.z, b1.w};
#pragma unroll
            for (int i = 0; i < 8; ++i)
#pragma unroll
                for (int j = 0; j < 8; ++j)
                    acc[i][j] = fmaf(av[i], bv[j], acc[i][j]);
        }
        __syncthreads();
    }
    // epilogue: m = m0 + iq*64 + tm*4 + i', n = n0 + jq*64 + tn*4 + j'
    bool fullN = (n0 + 128 <= N);
#pragma unroll
    for (int iq = 0; iq < 2; ++iq) {
        int mb = m0 + iq * 64 + tm * 4;
        if (mb >= M) continue;
        if (mb < twoCo) {
#pragma unroll
            for (int jq = 0; jq < 2; ++jq)
#pragma unroll
                for (int jj = 0; jj < 4; ++jj) {
                    int n = n0 + jq * 64 + tn * 4 + jj;
                    if (n < N) {
                        float4 v = make_float4(acc[iq * 4 + 0][jq * 4 + jj],
                                               acc[iq * 4 + 1][jq * 4 + jj],
                                               acc[iq * 4 + 2][jq * 4 + jj],
                                               acc[iq * 4 + 3][jq * 4 + jj]);
                        *(float4*)&qk[((size_t)b * N + n) * twoCo + mb] = v;
                    }
                }
        } else {
#pragma unroll
            for (int i = 0; i < 4; ++i) {
                int row = mb + i - twoCo;
                float* zp = &z[((size_t)b * Mz + row) * N];
#pragma unroll
                for (int jq = 0; jq < 2; ++jq) {
                    int nb_ = n0 + jq * 64 + tn * 4;
                    if (fullN) {
                        *(float4*)&zp[nb_] = make_float4(acc[iq * 4 + i][jq * 4 + 0],
                                                         acc[iq * 4 + i][jq * 4 + 1],
                                                         acc[iq * 4 + i][jq * 4 + 2],
                                                         acc[iq * 4 + i][jq * 4 + 3]);
                    } else {
#pragma unroll
                        for (int jj = 0; jj < 4; ++jj)
                            if (nb_ + jj < N) zp[nb_ + jj] = acc[iq * 4 + i][jq * 4 + jj];
                    }
                }
            }
        }
    }
}

// ---- attention scores + softmax, thread per (n, tap) -----------------------
template <int KH, int KW, int CO, int NPB>
__global__ void attn_v3_kernel(const float* __restrict__ qk,  // [b][HWin][2CO]
                               float* __restrict__ attn,      // [b][K][Nout]
                               int H, int W, int Ho, int Wo, int pt, int pl) {
    const int K = KH * KW;
    __shared__ float ssh[NPB][K];
    int tid = threadIdx.x;
    int b = blockIdx.y;
    int ln = tid / K, t = tid - ln * K;
    int Nout = Ho * Wo;
    int n = blockIdx.x * NPB + ln;
    bool active = (tid < NPB * K) && (n < Nout);
    int HWin = H * W;
    float sv = 0.f;
    if (active) {
        int ho = n / Wo, wo = n - ho * Wo;
        int row = ho + t / KW - pt, col = wo + t % KW - pl;
        if (row >= 0 && row < H && col >= 0 && col < W) {
            const float* qp = qk + ((size_t)b * HWin + ho * W + wo) * (2 * CO);
            const float* kp = qk + ((size_t)b * HWin + (size_t)row * W + col) * (2 * CO) + CO;
#pragma unroll
            for (int o = 0; o < CO; o += 4) {
                float4 q4 = *(const float4*)(qp + o);
                float4 k4 = *(const float4*)(kp + o);
                sv += q4.x * k4.x + q4.y * k4.y + q4.z * k4.z + q4.w * k4.w;
            }
        }
        ssh[ln][t] = sv;
    }
    __syncthreads();
    if (active) {
        float mx = ssh[ln][0];
#pragma unroll
        for (int tt = 1; tt < K; ++tt) mx = fmaxf(mx, ssh[ln][tt]);
        float sum = 0.f;
#pragma unroll
        for (int tt = 0; tt < K; ++tt) sum += expf(ssh[ln][tt] - mx);
        float num = expf(sv - mx);
        attn[((size_t)b * K + t) * Nout + n] = num / sum;
    }
}

// ---- combine + BN partials: out = sum_t attn[t] * shifted z[t] -------------
template <int KH, int KW>
__global__ void combine_stats_kernel(const float* __restrict__ z,    // [b][Mz][HWin]
                                     const float* __restrict__ attn, // [b][K][Nout]
                                     float* __restrict__ out,        // [b][Co][Nout]
                                     float2* __restrict__ part,      // [Co][B*nbx]
                                     int Co, int Mz,
                                     int H, int W, int Ho, int Wo,
                                     int pt, int pl) {
    const int K = KH * KW;
    int tid = threadIdx.x;
    int bc = blockIdx.y;
    int b = bc / Co, o = bc - b * Co;
    int Nout = Ho * Wo, Nin = H * W;
    int n = blockIdx.x * blockDim.x + tid;
    float val = 0.f;
    if (n < Nout) {
        int ho = n / Wo, wo = n - ho * Wo;
#pragma unroll
        for (int dk = 0; dk < KH; ++dk) {
            int row = ho + dk - pt;
            if (row < 0 || row >= H) continue;
#pragma unroll
            for (int dl = 0; dl < KW; ++dl) {
                int col = wo + dl - pl;
                if (col < 0 || col >= W) continue;
                int t = dk * KW + dl;
                float a = attn[((size_t)b * K + t) * Nout + n];
                float zv = z[((size_t)b * Mz + t * Co + o) * Nin + row * W + col];
                val = fmaf(a, zv, val);
            }
        }
        out[((size_t)b * Co + o) * Nout + n] = val;
    }
    __shared__ float sh[TPB], sh2[TPB];
    sh[tid] = (n < Nout) ? val : 0.f;
    sh2[tid] = (n < Nout) ? val * val : 0.f;
    __syncthreads();
    for (int st = TPB / 2; st > 0; st >>= 1) {
        if (tid < st) { sh[tid] += sh[tid + st]; sh2[tid] += sh2[tid + st]; }
        __syncthreads();
    }
    if (tid == 0) {
        int chunk = b * gridDim.x + blockIdx.x;
        part[(size_t)o * (2 * gridDim.x) + chunk] = make_float2(sh[0], sh2[0]);
    }
}

// ---- bn + relu + stride-2 subsample ----------------------------------------
__global__ void bn_pool_kernel(const float* __restrict__ x,  // [B,C,H,W]
                               const float* __restrict__ mr,
                               const float* __restrict__ g,
                               const float* __restrict__ bb,
                               float* __restrict__ y,        // [B,C,H2,W2]
                               int B, int C, int H, int W, int H2, int W2) {
    int idx = blockIdx.x * blockDim.x + threadIdx.x;
    int N = B * C * H2 * W2;
    if (idx >= N) return;
    int w2 = idx % W2; int r = idx / W2;
    int h2 = r % H2; r /= H2;
    int c = r % C; int b = r / C;
    float v = x[(((long long)b * C + c) * H + 2 * h2) * W + 2 * w2];
    float yn = (v - mr[c]) * mr[C + c] * g[c] + bb[c];
    y[idx] = fmaxf(yn, 0.f);
}

// ---- final: BN finalize (inline) + bn+relu + AvgPool(1,56) -----------------
__global__ void bn_avg_final_kernel(const float* __restrict__ x, // [B,C,1,W]
                                    const float2* __restrict__ part, // [C][NCH]
                                    const float* __restrict__ g,
                                    const float* __restrict__ bb,
                                    float* __restrict__ out,     // [B,C,1,nW]
                                    int B, int C, int W, int nW, int NCH) {
    int idx = blockIdx.x * blockDim.x + threadIdx.x;
    int N = B * C * nW;
    if (idx >= N) return;
    int j = idx % nW; int r = idx / nW;
    int c = r % C; int b = r / C;
    double s = 0.0, s2 = 0.0;
    for (int i = 0; i < NCH; ++i) {
        float2 p = part[(size_t)c * NCH + i];
        s += p.x; s2 += p.y;
    }
    double cnt = (double)B * W;
    double mean = s / cnt;
    double var = s2 / cnt - mean * mean;
    float rstd = (float)(1.0 / sqrt(var + 1e-5));
    float meanf = (float)mean, gg = g[c], bo = bb[c];
    const float* xb = x + ((long long)b * C + c) * W + j * 56;
    float acc = 0.f;
    for (int i = 0; i < 56; ++i) {
        float yn = (xb[i] - meanf) * rstd * gg + bo;
        acc += fmaxf(yn, 0.f);
    }
    out[idx] = acc * (1.f / 56.f);
}

// ---------------------------------------------------------------------------
extern "C" void kernel_launch(void* const* d_in, const int* in_sizes, int n_in,
                              void* d_out, int out_size, void* d_ws, size_t ws_size,
                              hipStream_t stream) {
    const float* x   = (const float*)d_in[0];
    const float* qw0 = (const float*)d_in[1];
    const float* kw0 = (const float*)d_in[2];
    const float* vw0 = (const float*)d_in[3];
    const float* ea0 = (const float*)d_in[4];
    const float* eb0 = (const float*)d_in[5];
    const float* em0 = (const float*)d_in[6];
    const float* g0  = (const float*)d_in[7];
    const float* b0  = (const float*)d_in[8];
    const float* qw1 = (const float*)d_in[9];
    const float* kw1 = (const float*)d_in[10];
    const float* vw1 = (const float*)d_in[11];
    const float* ea1 = (const float*)d_in[12];
    const float* eb1 = (const float*)d_in[13];
    const float* em1 = (const float*)d_in[14];
    const float* g1  = (const float*)d_in[15];
    const float* b1  = (const float*)d_in[16];
    const float* qw2 = (const float*)d_in[17];
    const float* kw2 = (const float*)d_in[18];
    const float* vw2 = (const float*)d_in[19];
    const float* ea2 = (const float*)d_in[20];
    const float* eb2 = (const float*)d_in[21];
    const float* em2 = (const float*)d_in[22];
    const float* g2  = (const float*)d_in[23];
    const float* b2  = (const float*)d_in[24];
    float* outp = (float*)d_out;
    (void)ws_size; (void)in_sizes; (void)n_in; (void)out_size;

    float* ws = (float*)d_ws;
    size_t off = 0;
    auto alloc = [&](size_t n) { float* p = ws + off; off += (n + 63) & ~(size_t)63; return p; };

    // s0 (3.07M, dead before stage-1 GEMM) overlaps z1 (15.36M) in one arena.
    float* arena = alloc(2 * 1280 * 6000);
    float* s0    = arena;                   // [2][64][24000]
    float* z1    = arena;                   // [2][1280][6000]

    float* par0   = alloc(321);             // c0 + vweff0
    float* part0  = alloc(64 * 188 * 2);    // float2 [64][188]
    float* part1  = alloc(128 * 48 * 2);    // float2 [128][48]
    float* part2  = alloc(16 * 6 * 2);      // float2 [16][6]
    float* mr0    = alloc(2 * 64);
    float* h0     = alloc(2 * 64 * 6000);   // [2][64][4*1500]
    float* Wcat1  = alloc(1536 * 64);
    float* qk1    = alloc(2 * 6000 * 256);
    float* attn1  = alloc(2 * 10 * 6000);
    float* s1     = alloc(2 * 128 * 6000);
    float* mr1    = alloc(2 * 128);
    float* h1     = alloc(2 * 128 * 1500);
    float* Wcat2  = alloc(192 * 128);
    float* qk2    = alloc(2 * 1500 * 32);
    float* z2     = alloc(2 * 160 * 1500);
    float* attn2  = alloc(2 * 10 * 750);
    float* s2     = alloc(2 * 16 * 750);

    auto grid = [](int n) { return (n + TPB - 1) / TPB; };

    // ======== stage 0: B=2 Cin=1 H=8 W=3000, Co=64, kh=1 kw=5, pad(2,2,0,0)
    prep0_kernel<<<1, TPB, 0, stream>>>(ea0, eb0, em0, qw0, kw0, vw0, par0);
    {
        dim3 g(94, 2);
        attn_out0_kernel<<<g, TPB, 0, stream>>>(x, par0, s0, (float2*)part0);
    }
    // prep_wcat1 also finalizes stage-0 BN stats (mr0 from part0)
    prep_wcat_kernel<<<96, TPB, 0, stream>>>(ea1, eb1, em1, qw1, kw1, vw1, Wcat1,
        128, 2, 5, 64, (const float2*)part0, mr0, 64, 188, 48000);
    bn_pool_kernel<<<grid(2 * 64 * 6000), TPB, 0, stream>>>(s0, mr0, g0, b0, h0,
        2, 64, 8, 3000, 4, 1500);

    // ======== stage 1: Cin=64 H=4 W=1500, Co=128, kh=2 kw=5, pad(2,2,1,1)
    {
        dim3 g((6000 + 127) / 128, 1536 / 128, 2);
        gemm_qkz_kernel<<<g, TPB, 0, stream>>>(Wcat1, h0, qk1, z1, 1536, 6000, 64, 256);
    }
    {
        dim3 g(6000 / 25, 2);
        attn_v3_kernel<2, 5, 128, 25><<<g, TPB, 0, stream>>>(qk1, attn1,
            4, 1500, 4, 1500, 1, 2);
    }
    {
        dim3 g(24, 2 * 128);   // nbx=24 (24*256=6144>=6000), NCH1=48
        combine_stats_kernel<2, 5><<<g, TPB, 0, stream>>>(z1, attn1, s1,
            (float2*)part1, 128, 1280, 4, 1500, 4, 1500, 1, 2);
    }
    // prep_wcat2 also finalizes stage-1 BN stats (mr1 from part1)
    prep_wcat_kernel<<<24, TPB, 0, stream>>>(ea2, eb2, em2, qw2, kw2, vw2, Wcat2,
        16, 2, 5, 128, (const float2*)part1, mr1, 128, 48, 12000);
    bn_pool_kernel<<<grid(2 * 128 * 1500), TPB, 0, stream>>>(s1, mr1, g1, b1, h1,
        2, 128, 4, 1500, 2, 750);

    // ======== stage 2: Cin=128 H=2 W=750, Co=16, kh=2 kw=5, pad(2,2,0,0)
    {
        dim3 g((1500 + 127) / 128, (192 + 127) / 128, 2);
        gemm_qkz_kernel<<<g, TPB, 0, stream>>>(Wcat2, h1, qk2, z2, 192, 1500, 128, 32);
    }
    {
        dim3 g(750 / 25, 2);
        attn_v3_kernel<2, 5, 16, 25><<<g, TPB, 0, stream>>>(qk2, attn2,
            2, 750, 1, 750, 0, 2);
    }
    {
        dim3 g(3, 2 * 16);     // nbx=3 (3*256=768>=750), NCH2=6
        combine_stats_kernel<2, 5><<<g, TPB, 0, stream>>>(z2, attn2, s2,
            (float2*)part2, 16, 160, 2, 750, 1, 750, 0, 2);
    }
    bn_avg_final_kernel<<<grid(2 * 16 * 13), TPB, 0, stream>>>(s2, (const float2*)part2,
        g2, b2, outp, 2, 16, 750, 13, 6);
}